// Round 1
// baseline (111.285 us; speedup 1.0000x reference)
//
#include <hip/hip_runtime.h>
#include <math.h>

#define NN 512
#define MM 31
#define TT 32            // M+1 tokens per node
#define EE 64            // INP = EMB = ATT
#define NREL 200
#define NMAT 201
#define SELF_LOOP 200
#define QCAP 192         // per-relation capacity (mean ~82, ~12 sigma)
#define NT 6             // 32-token tiles per relation
#define WSTR 72          // bf16 LDS row stride (16B-aligned, de-aliased banks)
#define CPAD 32          // one counter per 128B line (round-6 verified win)

typedef short  short8 __attribute__((ext_vector_type(8)));
typedef float  f32x4  __attribute__((ext_vector_type(4)));

__device__ __forceinline__ unsigned short f2bf(float f) {
    union { float f; unsigned int u; } a; a.f = f;
    unsigned int r = a.u + 0x7FFFu + ((a.u >> 16) & 1u);   // RNE
    return (unsigned short)(r >> 16);
}
__device__ __forceinline__ float bf2f(unsigned short u) {
    union { unsigned int u; float f; } a; a.u = ((unsigned int)u) << 16;
    return a.f;
}

// ---------------------------------------------------------------------------
// prep_convert: grid = 603 converter blocks + 512 node blocks.
//  bid < 603:  one [64,64] f32 Q/K/V matrix -> transposed bf16 Wt[a][e]
//  bid >= 603: node n: scan labels into buckets (padded counters),
//              msg[n] -> bf16 (coalesced), curr = h@W_self -> bf16,
//              k[n][0] = curr@K[200] -> bf16.
// ---------------------------------------------------------------------------
__global__ __launch_bounds__(256) void prep_convert_kernel(
    const float* __restrict__ h, const float* __restrict__ W_self,
    const float* __restrict__ Q, const float* __restrict__ K,
    const float* __restrict__ V,
    const int* __restrict__ msg_type, const int* __restrict__ r_label_node,
    const int* __restrict__ r_label_msg, const float* __restrict__ msg,
    int* __restrict__ cnt_q, int* __restrict__ cnt_k,
    int* __restrict__ list_q, int* __restrict__ list_k,
    unsigned short* __restrict__ wt_q, unsigned short* __restrict__ wt_k,
    unsigned short* __restrict__ wt_v,
    unsigned short* __restrict__ msg_bf, unsigned short* __restrict__ curr_bf,
    unsigned short* __restrict__ k_bf)
{
    const int bid = blockIdx.x, tid = threadIdx.x;

    if (bid < 3 * NMAT) {
        // ---- converter: one [64,64] f32 -> transposed bf16 Wt[a][e] ----
        const int r   = bid % NMAT;
        const int mat = bid / NMAT;
        const float* src = (mat == 0 ? Q : mat == 1 ? K : V) + (size_t)r * EE * EE;
        unsigned short* dst = (mat == 0 ? wt_q : mat == 1 ? wt_k : wt_v)
                              + (size_t)r * EE * EE;
        __shared__ unsigned short t_s[EE * WSTR];
        {
            const int e = tid >> 2, aseg = (tid & 3) * 16;
            const float4* s4 = (const float4*)(src + e * EE + aseg);
            float4 f0 = s4[0], f1 = s4[1], f2 = s4[2], f3 = s4[3];
            unsigned short b[16] = {
                f2bf(f0.x), f2bf(f0.y), f2bf(f0.z), f2bf(f0.w),
                f2bf(f1.x), f2bf(f1.y), f2bf(f1.z), f2bf(f1.w),
                f2bf(f2.x), f2bf(f2.y), f2bf(f2.z), f2bf(f2.w),
                f2bf(f3.x), f2bf(f3.y), f2bf(f3.z), f2bf(f3.w) };
            unsigned short* d = &t_s[e * WSTR + aseg];
            *(short8*)d = *(short8*)&b[0];
            *(short8*)(d + 8) = *(short8*)&b[8];
        }
        __syncthreads();
        {
            const int a = tid >> 2, eseg = (tid & 3) * 16;
            unsigned short o[16];
#pragma unroll
            for (int j = 0; j < 16; ++j)
                o[j] = t_s[(eseg + j) * WSTR + a];
            unsigned short* d = dst + a * EE + eseg;
            *(short8*)d = *(short8*)&o[0];
            *(short8*)(d + 8) = *(short8*)&o[8];
        }
        return;
    }

    // ---- node block ----
    const int n = bid - 3 * NMAT;

    // scan labels into padded relation buckets
    if (tid < MM) {
        int j  = n * MM + tid;
        int rl = r_label_msg[j];
        int p  = atomicAdd(&cnt_q[rl * CPAD], 1);
        if (p < QCAP) list_q[rl * QCAP + p] = n * TT + tid + 1;
        int mt = msg_type[j];
        int p2 = atomicAdd(&cnt_k[mt * CPAD], 1);
        if (p2 < QCAP) list_k[mt * QCAP + p2] = n * TT + tid + 1;
    } else if (tid == 63) {
        int r = r_label_node[n];
        int p = atomicAdd(&cnt_q[r * CPAD], 1);
        if (p < QCAP) list_q[r * QCAP + p] = n * TT;
    }

    // msg[n] -> bf16 (31*64 = 1984 floats; threads 0..247 do 8 each, coalesced)
    if (tid < MM * EE / 8) {
        const float4* s4 = (const float4*)(msg + (size_t)n * MM * EE) + tid * 2;
        float4 f0 = s4[0], f1 = s4[1];
        unsigned short b[8] = { f2bf(f0.x), f2bf(f0.y), f2bf(f0.z), f2bf(f0.w),
                                f2bf(f1.x), f2bf(f1.y), f2bf(f1.z), f2bf(f1.w) };
        *(short8*)(msg_bf + (size_t)n * MM * EE + tid * 8) = *(short8*)b;
    }

    // curr = h[n] @ W_self (f32 accum), publish bf16; k0 = curr @ K[200]
    __shared__ float c_s[EE];
    if (tid < EE) {
        const float* hrow = h + n * EE;
        float acc = 0.f;
#pragma unroll 8
        for (int e = 0; e < EE; ++e)
            acc = fmaf(hrow[e], W_self[e * EE + tid], acc);
        curr_bf[n * EE + tid] = f2bf(acc);
        c_s[tid] = acc;
    }
    __syncthreads();
    if (tid < EE) {
        const float* K200 = K + (size_t)SELF_LOOP * EE * EE;
        float k0 = 0.f;
#pragma unroll 8
        for (int e = 0; e < EE; ++e)
            k0 = fmaf(c_s[e], K200[e * EE + tid], k0);
        k_bf[(size_t)n * TT * EE + tid] = f2bf(k0);
    }
}

// ---------------------------------------------------------------------------
// proj_tile: block = (relation r, tile t). 32 q-tokens AND 32 k-tokens via
// 16x16x32 bf16 MFMA. v2: ZERO LDS, ZERO syncs — all fragments are loaded
// straight from global (Wt rows and gathered token rows are both contiguous
// 16B-per-lane patterns; everything is L2/L3-hot from prep).
//   A[m=lane&15][k=(lane>>4)*8+j], B[k][n=lane&15] from Wt[a=n][e=k],
//   C: col=lane&15, row=(lane>>4)*4+reg  (verified rounds 3-7)
// ---------------------------------------------------------------------------
__global__ __launch_bounds__(256) void proj_tile_kernel(
    const unsigned short* __restrict__ curr_bf,
    const unsigned short* __restrict__ msg_bf,
    const unsigned short* __restrict__ wt_q,
    const unsigned short* __restrict__ wt_k,
    const unsigned short* __restrict__ wt_v,
    const int* __restrict__ cnt_q, const int* __restrict__ cnt_k,
    const int* __restrict__ list_q, const int* __restrict__ list_k,
    unsigned short* __restrict__ q_bf, unsigned short* __restrict__ k_bf,
    unsigned short* __restrict__ v_bf)
{
    const int r    = blockIdx.x / NT;
    const int tile = blockIdx.x % NT;
    const int tid  = threadIdx.x;
    const int lane = tid & 63;
    const int wave = tid >> 6;
    const int col  = lane & 15;
    const int quad = lane >> 4;

    const int nq = min(cnt_q[r * CPAD], QCAP);
    const int nk = min(cnt_k[r * CPAD], QCAP);
    const int q0 = tile * 32;
    const bool do_q = q0 < nq;
    const bool do_k = q0 < nk;
    if (!do_q && !do_k) return;

    const size_t wbase = (size_t)r * EE * EE;

    // ---- q/v side (wave: mtile = w&1, mat = w>>1) ----
    if (do_q) {
        const int mtile = wave & 1;
        const unsigned short* wmat = ((wave >> 1) ? wt_v : wt_q) + wbase;
        unsigned short* outp = (wave >> 1) ? v_bf : q_bf;
        const int arow = q0 + mtile * 16 + col;
        int atok = (arow < nq) ? list_q[r * QCAP + arow] : 0;
        {
            int an = atok >> 5, at = atok & 31;
            const unsigned short* aptr = at
                ? (msg_bf + ((size_t)an * MM + (at - 1)) * EE)
                : (curr_bf + (size_t)an * EE);
            f32x4 acc[4] = {{0,0,0,0},{0,0,0,0},{0,0,0,0},{0,0,0,0}};
#pragma unroll
            for (int kk = 0; kk < 2; ++kk) {
                short8 af = *(const short8*)(aptr + kk * 32 + quad * 8);
#pragma unroll
                for (int nt = 0; nt < 4; ++nt) {
                    short8 bf = *(const short8*)(wmat + (nt * 16 + col) * EE + kk * 32 + quad * 8);
                    acc[nt] = __builtin_amdgcn_mfma_f32_16x16x32_bf16(af, bf, acc[nt], 0, 0, 0);
                }
            }
#pragma unroll
            for (int reg = 0; reg < 4; ++reg) {
                int rrow = q0 + mtile * 16 + quad * 4 + reg;
                if (rrow < nq) {
                    int token = list_q[r * QCAP + rrow];
#pragma unroll
                    for (int nt = 0; nt < 4; ++nt)
                        outp[(size_t)token * EE + nt * 16 + col] = f2bf(acc[nt][reg]);
                }
            }
        }
    }

    // ---- k side (wave: mtile = w&1, n-half = w>>1) ----
    if (do_k) {
        const int mtile = wave & 1;
        const int nh = wave >> 1;
        const int arow = q0 + mtile * 16 + col;
        int atok = (arow < nk) ? list_k[r * QCAP + arow] : 0;
        int an = atok >> 5, at = atok & 31;
        const unsigned short* aptr = at
            ? (msg_bf + ((size_t)an * MM + (at - 1)) * EE)
            : (curr_bf + (size_t)an * EE);
        const unsigned short* wmat = wt_k + wbase;
        f32x4 acc[2] = {{0,0,0,0},{0,0,0,0}};
#pragma unroll
        for (int kk = 0; kk < 2; ++kk) {
            short8 af = *(const short8*)(aptr + kk * 32 + quad * 8);
#pragma unroll
            for (int j = 0; j < 2; ++j) {
                int nt = nh * 2 + j;
                short8 bf = *(const short8*)(wmat + (nt * 16 + col) * EE + kk * 32 + quad * 8);
                acc[j] = __builtin_amdgcn_mfma_f32_16x16x32_bf16(af, bf, acc[j], 0, 0, 0);
            }
        }
#pragma unroll
        for (int reg = 0; reg < 4; ++reg) {
            int rrow = q0 + mtile * 16 + quad * 4 + reg;
            if (rrow < nk) {
                int token = list_k[r * QCAP + rrow];
#pragma unroll
                for (int j = 0; j < 2; ++j)
                    k_bf[(size_t)token * EE + (nh * 2 + j) * 16 + col] = f2bf(acc[j][reg]);
            }
        }
    }
}

// ---------------------------------------------------------------------------
// attn v2: one block per node. Scores 32x32 = q @ k^T via 4 MFMA tiles read
// DIRECTLY from global (both A and B fragments are row-major 16B/lane reads:
// B[k][n] = k_row[n][k]). No q/k/v LDS staging; v consumed from global in
// the pooled reduction (only att row 0 is needed).
// ---------------------------------------------------------------------------
__global__ __launch_bounds__(256) void attn_kernel(
    const unsigned short* __restrict__ q_bf,
    const unsigned short* __restrict__ k_bf,
    const unsigned short* __restrict__ v_bf,
    const float* __restrict__ ffn_w, const float* __restrict__ ffn_b,
    float* __restrict__ out)
{
    const int n = blockIdx.x, tid = threadIdx.x;
    const int lane = tid & 63, wave = tid >> 6;
    const int col = lane & 15, quad = lane >> 4;
    __shared__ float s_s[TT][TT + 1];
    __shared__ float att0[TT];
    __shared__ float pooled[EE];

    {   // scores: wave w -> tile (mi = w&1, ni = w>>1)
        const int mi = wave & 1, ni = wave >> 1;
        const unsigned short* qrow = q_bf + ((size_t)n * TT + mi * 16 + col) * EE;
        const unsigned short* krow = k_bf + ((size_t)n * TT + ni * 16 + col) * EE;
        f32x4 acc = {0, 0, 0, 0};
#pragma unroll
        for (int kk = 0; kk < 2; ++kk) {
            short8 a = *(const short8*)(qrow + kk * 32 + quad * 8);
            short8 b = *(const short8*)(krow + kk * 32 + quad * 8);
            acc = __builtin_amdgcn_mfma_f32_16x16x32_bf16(a, b, acc, 0, 0, 0);
        }
#pragma unroll
        for (int reg = 0; reg < 4; ++reg)
            s_s[mi * 16 + quad * 4 + reg][ni * 16 + col] = acc[reg] * 0.125f;
    }
    __syncthreads();

    // softmax over the QUERY axis per column; only row 0 of att needed
    if (tid < TT) {
        float mx = -INFINITY;
#pragma unroll
        for (int qi = 0; qi < TT; ++qi) mx = fmaxf(mx, s_s[qi][tid]);
        float sum = 0.f;
#pragma unroll
        for (int qi = 0; qi < TT; ++qi) sum += __expf(s_s[qi][tid] - mx);
        att0[tid] = __expf(s_s[0][tid] - mx) / sum;
    }
    __syncthreads();

    if (tid < EE) {
        const unsigned short* vp = v_bf + (size_t)n * TT * EE + tid;
        float acc = 0.f;
#pragma unroll 8
        for (int ki = 0; ki < TT; ++ki)
            acc = fmaf(att0[ki], bf2f(vp[ki * EE]), acc);
        pooled[tid] = acc;
    }
    __syncthreads();

    if (tid < EE) {
        float acc = ffn_b[tid];
#pragma unroll 8
        for (int a = 0; a < EE; ++a)
            acc = fmaf(pooled[a], ffn_w[a * EE + tid], acc);
        out[n * EE + tid] = acc;
    }
}

extern "C" void kernel_launch(void* const* d_in, const int* in_sizes, int n_in,
                              void* d_out, int out_size, void* d_ws, size_t ws_size,
                              hipStream_t stream) {
    const float* h            = (const float*)d_in[0];
    const float* msg          = (const float*)d_in[1];
    const int*   msg_type     = (const int*)  d_in[2];
    const int*   r_label_node = (const int*)  d_in[3];
    const int*   r_label_msg  = (const int*)  d_in[4];
    const float* W_self       = (const float*)d_in[5];
    const float* Q            = (const float*)d_in[6];
    const float* K            = (const float*)d_in[7];
    const float* V            = (const float*)d_in[8];
    const float* ffn_w        = (const float*)d_in[9];
    const float* ffn_b        = (const float*)d_in[10];
    float*       out          = (float*)d_out;

    // ws layout (16B aligned): counters | lists | bf16 weights | bf16 tensors
    int* cnt_q  = (int*)d_ws;                          // [200*CPAD]
    int* cnt_k  = cnt_q + NREL * CPAD;                 // [200*CPAD]
    int* list_q = cnt_k + NREL * CPAD;                 // [200*QCAP]
    int* list_k = list_q + NREL * QCAP;                // [200*QCAP]
    unsigned short* wt_q = (unsigned short*)(list_k + NREL * QCAP);
    unsigned short* wt_k = wt_q + (size_t)NMAT * EE * EE;
    unsigned short* wt_v = wt_k + (size_t)NMAT * EE * EE;
    unsigned short* msg_bf  = wt_v + (size_t)NMAT * EE * EE;     // [512*31*64]
    unsigned short* curr_bf = msg_bf + (size_t)NN * MM * EE;     // [512*64]
    unsigned short* q_bf = curr_bf + NN * EE;                    // [512*32*64]
    unsigned short* k_bf = q_bf + (size_t)NN * TT * EE;
    unsigned short* v_bf = k_bf + (size_t)NN * TT * EE;

    hipMemsetAsync(cnt_q, 0, 2 * NREL * CPAD * sizeof(int), stream);
    prep_convert_kernel<<<3 * NMAT + NN, 256, 0, stream>>>(
        h, W_self, Q, K, V, msg_type, r_label_node, r_label_msg, msg,
        cnt_q, cnt_k, list_q, list_k, wt_q, wt_k, wt_v,
        msg_bf, curr_bf, k_bf);
    proj_tile_kernel<<<NREL * NT, 256, 0, stream>>>(
        curr_bf, msg_bf, wt_q, wt_k, wt_v, cnt_q, cnt_k, list_q, list_k,
        q_bf, k_bf, v_bf);
    attn_kernel<<<NN, 256, 0, stream>>>(q_bf, k_bf, v_bf, ffn_w, ffn_b, out);
}